// Round 13
// baseline (181.495 us; speedup 1.0000x reference)
//
#include <hip/hip_runtime.h>
#include <stdint.h>

// PASSED baseline (r12): 198us, VALUBusy ~103%, pure VALU-issue-bound.
// This round: instruction-count reduction.
//  - 2048 blocks (512 o x 4 bgroups); each wave sweeps 16 rows -> phase-1 +
//    subkey threefry overhead amortized (was ~30% of all calls at 32768 blocks).
//  - rotl via __builtin_rotateleft32 -> v_alignbit_b32 (1 op/rotate).
//  - exp(logit+g) = exp2(lscaled - log2(-log2(u))), lscaled cached in 8 regs
//    per block (o fixed): per-sample epilogue ~8 VALU + 3 trans.
//  - selv: exactly one lane holds it -> single __shfl, no reduce.
// All transcendentals via raw ISA (v_log_f32/v_exp_f32) — NO libm (H_libm:
// this pod hangs compiling any ocml-dependent source; proven r0-r12).
// Math (forward reduction, verified absmax 7.6e-6 in r12):
//   i*(o) = argmax_i(logits[o,i]+g1[o,i]); c[o] = 2*tanh(2*tanh(weight[o,i*]))
//   y[b,o] = c[o]*x[b,i*]*softmax(logits[o,:]+g2[b,o,:])[i*]
// RNG: JAX partitionable threefry2x32; key(42)=(0,42), kg_j=tf(key,(0,j)),
//   bits[e]=o0^o1 of tf(kg,(0,e)).

__device__ __forceinline__ float fast_log2(float x) {
  float r; asm("v_log_f32 %0, %1" : "=v"(r) : "v"(x)); return r;
}
__device__ __forceinline__ float fast_exp2(float x) {
  float r; asm("v_exp_f32 %0, %1" : "=v"(r) : "v"(x)); return r;
}
__device__ __forceinline__ float fast_tanh(float w) {  // (t-1)/(t+1), t=e^2w
  float t = fast_exp2(w * 2.8853900817779268f);
  return (t - 1.0f) / (t + 1.0f);
}

__device__ __forceinline__ uint32_t rotl(uint32_t x, int r) {
  return __builtin_rotateleft32(x, (unsigned)r);
}

__device__ __forceinline__ void threefry2x32(uint32_t k0, uint32_t k1,
                                             uint32_t x0, uint32_t x1,
                                             uint32_t& o0, uint32_t& o1) {
  const uint32_t ks2 = k0 ^ k1 ^ 0x1BD11BDAu;
  x0 += k0; x1 += k1;
  const int rotA[4] = {13, 15, 26, 6};
  const int rotB[4] = {17, 29, 16, 24};
#pragma unroll
  for (int g = 0; g < 5; ++g) {
    const int* rots = (g & 1) ? rotB : rotA;
#pragma unroll
    for (int r = 0; r < 4; ++r) {
      x0 += x1; x1 = rotl(x1, rots[r]); x1 ^= x0;
    }
    const uint32_t ks[3] = {k0, k1, ks2};
    x0 += ks[(g + 1) % 3];
    x1 += ks[(g + 2) % 3] + (uint32_t)(g + 1);
  }
  o0 = x0; o1 = x1;
}

__device__ __forceinline__ uint32_t tf_bits(uint32_t ka, uint32_t kb, uint32_t e) {
  uint32_t r0, r1;
  threefry2x32(ka, kb, 0u, e, r0, r1);
  return r0 ^ r1;
}

// -log2(-log2(u)) path pieces; NaN-guarded against HW-log returning exact 0.
__device__ __forceinline__ float neglog2_from_bits(uint32_t bits) {
  // returns l2 = log2(max(-log2(u), 1e-37)), u = frac(bits) + tiny
  float f  = __uint_as_float((bits >> 9) | 0x3f800000u) - 1.0f;
  float u  = f + 1.17549435e-38f;
  float l1 = fast_log2(u);                 // < 0
  float nl = fmaxf(-l1, 1e-37f);
  return fast_log2(nl);
}

// grid: 2048 blocks = 512 o x 4 bgroups; 256 threads (4 waves).
// Wave w of block (o,bg) handles rows b = bg*64 + w*16 + it, it=0..15.
__global__ __launch_bounds__(256) void k_fused(const float* __restrict__ x,
                                               const float* __restrict__ weight,
                                               const float* __restrict__ logits,
                                               float* __restrict__ out) {
  const int o    = blockIdx.x & 511;
  const int bg   = blockIdx.x >> 9;   // 0..3
  const int tid  = threadIdx.x;
  const int lane = tid & 63;
  const int wid  = tid >> 6;
  const float* lrow = logits + o * 512;

  // subkeys (fold-like split of key(42) = (0,42)); once per thread, amortized
  uint32_t k1a, k1b, k2a, k2b;
  threefry2x32(0u, 42u, 0u, 0u, k1a, k1b);  // kg1 for g1 (OUT,IN)
  threefry2x32(0u, 42u, 0u, 1u, k2a, k2b);  // kg2 for g2 (B,OUT,IN)

  // ---- phase 1 (block-cooperative): i* = argmax_i(logits[o,i] + g1[o,i]) ----
  float v; int idx;
  {
    const uint32_t e0 = (uint32_t)(o * 512 + tid);
    // g1 = 0.36651292 - ln2 * l2   (= -ln(-ln u))
    float g1a = fmaf(-0.69314718056f, neglog2_from_bits(tf_bits(k1a, k1b, e0)),
                     0.3665129206f);
    v   = lrow[tid] + g1a;
    idx = tid;
    float g1b = fmaf(-0.69314718056f, neglog2_from_bits(tf_bits(k1a, k1b, e0 + 256u)),
                     0.3665129206f);
    float v2 = lrow[tid + 256] + g1b;
    if (v2 > v) { v = v2; idx = tid + 256; }  // tie -> lower index (jnp.argmax)
  }
  for (int off = 32; off > 0; off >>= 1) {
    float ov = __shfl_down(v, off);
    int   oi = __shfl_down(idx, off);
    if (ov > v || (ov == v && oi < idx)) { v = ov; idx = oi; }
  }
  __shared__ float swv[4];
  __shared__ int   swi[4];
  __shared__ int   s_istar;
  __shared__ float s_c;
  if (lane == 0) { swv[wid] = v; swi[wid] = idx; }
  __syncthreads();
  if (tid == 0) {
    float bv = swv[0]; int bi = swi[0];
    for (int w = 1; w < 4; ++w)
      if (swv[w] > bv || (swv[w] == bv && swi[w] < bi)) { bv = swv[w]; bi = swi[w]; }
    s_istar = bi;
    s_c = 2.0f * fast_tanh(2.0f * fast_tanh(weight[o * 512 + bi]));
  }
  __syncthreads();
  const int   isel = s_istar;
  const float c    = s_c;

  // ---- cache scaled logits for this o in registers (block-constant) ----
  // ev = exp2(lsc[j] - l2), lsc = l*log2e - log2(ln2) = l*1.442695 + 0.52876637
  float lsc[8];
#pragma unroll
  for (int j = 0; j < 8; ++j)
    lsc[j] = fmaf(lrow[lane + 64 * j], 1.4426950408889634f, 0.5287663729f);

  // ---- phase 2: 16 rows per wave ----
  const int b0 = bg * 64 + wid * 16;
#pragma unroll 1
  for (int it = 0; it < 16; ++it) {
    const int b   = b0 + it;                   // 0..255
    const int row = (b << 9) | o;              // 0..131071
    const uint32_t base = (uint32_t)row << 9;  // < 2^26

    float sum = 0.0f, selv = 0.0f;
#pragma unroll
    for (int j = 0; j < 8; ++j) {
      const int i = lane + 64 * j;
      float l2 = neglog2_from_bits(tf_bits(k2a, k2b, base + (uint32_t)i));
      float ev = fast_exp2(lsc[j] - l2);       // = exp(logits[o,i] + g2)
      sum += ev;
      selv = (i == isel) ? ev : selv;
    }
    for (int off = 32; off > 0; off >>= 1) sum += __shfl_down(sum, off);
    selv = __shfl(selv, isel & 63);            // exactly one lane holds it
    if (lane == 0) out[row] = c * x[(b << 9) | isel] * selv / sum;
  }
}

extern "C" void kernel_launch(void* const* d_in, const int* in_sizes, int n_in,
                              void* d_out, int out_size, void* d_ws, size_t ws_size,
                              hipStream_t stream) {
  const float* x      = (const float*)d_in[0];
  const float* weight = (const float*)d_in[1];
  const float* logits = (const float*)d_in[2];
  float* out = (float*)d_out;
  k_fused<<<dim3(512 * 4), dim3(256), 0, stream>>>(x, weight, logits, out);
}